// Round 5
// baseline (268.718 us; speedup 1.0000x reference)
//
#include <hip/hip_runtime.h>
#include <hip/hip_bf16.h>
#include <cstdint>
#include <cstddef>

#define H_     8
#define KV_    4
#define D_     256
#define HID_   2560
#define S_     32
#define L_     8192
#define NQ_    64          // G*S query rows per kv head
#define LKEEP_ (L_ - S_)   // 8160
#define NCH_   128         // attention l-chunks of 64

// ---------------- Kernel A: QKV projection, K-split x32 into partials ----------------
// part[32][32][4096]; cols 0..2047 Wq, 2048..3071 Wk, 3072..4095 Wv.
// grid (8 col-tiles of 512, 32 k-splits of 80), block 256. 16-deep W prefetch ring.
__global__ __launch_bounds__(256) void k_qkv(
    const float* __restrict__ hidden,
    const float* __restrict__ Wq, const float* __restrict__ Wk, const float* __restrict__ Wv,
    float* __restrict__ part)
{
    const int col0  = blockIdx.x * 512;
    const int kbase = blockIdx.y * 80;
    const float* W; int ldw, wb;
    if (col0 < 2048)      { W = Wq; ldw = 2048; wb = col0; }
    else if (col0 < 3072) { W = Wk; ldw = 1024; wb = col0 - 2048; }
    else                  { W = Wv; ldw = 1024; wb = col0 - 3072; }
    const int tid = threadIdx.x;
    const int tc  = tid * 2;

    __shared__ __align__(16) float hsT[80][36];   // [k][row]
    for (int i = 0; i < 3; i++) {
        int idx = i * 256 + tid;
        if (idx < 640) {
            int r = idx / 20, c4 = idx % 20;
            float4 v = *(const float4*)&hidden[r * HID_ + kbase + c4 * 4];
            hsT[c4*4+0][r] = v.x; hsT[c4*4+1][r] = v.y;
            hsT[c4*4+2][r] = v.z; hsT[c4*4+3][r] = v.w;
        }
    }
    __syncthreads();

    const float* Wt = W + (size_t)kbase * ldw + wb + tc;
    float acc[32][2] = {};
#define FMABLK(k, wc) \
    _Pragma("unroll") for (int r4 = 0; r4 < 8; r4++) { \
      float4 h = *(const float4*)&hsT[(k)][r4*4]; \
      acc[r4*4+0][0] = fmaf(h.x, wc.x, acc[r4*4+0][0]); acc[r4*4+0][1] = fmaf(h.x, wc.y, acc[r4*4+0][1]); \
      acc[r4*4+1][0] = fmaf(h.y, wc.x, acc[r4*4+1][0]); acc[r4*4+1][1] = fmaf(h.y, wc.y, acc[r4*4+1][1]); \
      acc[r4*4+2][0] = fmaf(h.z, wc.x, acc[r4*4+2][0]); acc[r4*4+2][1] = fmaf(h.z, wc.y, acc[r4*4+2][1]); \
      acc[r4*4+3][0] = fmaf(h.w, wc.x, acc[r4*4+3][0]); acc[r4*4+3][1] = fmaf(h.w, wc.y, acc[r4*4+3][1]); }

    float2 wr[16];
    #pragma unroll
    for (int j = 0; j < 16; j++) wr[j] = *(const float2*)&Wt[(size_t)j * ldw];
    for (int ib = 0; ib < 64; ib += 16) {          // ib = 0,16,32,48
        #pragma unroll
        for (int j = 0; j < 16; j++) {
            float2 wc = wr[j];
            wr[j] = *(const float2*)&Wt[(size_t)(ib + j + 16) * ldw];
            FMABLK(ib + j, wc)
        }
    }
    #pragma unroll
    for (int j = 0; j < 16; j++) { float2 wc = wr[j]; FMABLK(64 + j, wc) }
#undef FMABLK

    float* op = part + (size_t)blockIdx.y * (32 * 4096);
    #pragma unroll
    for (int r = 0; r < 32; r++)
        *(float2*)&op[r * 4096 + col0 + tc] = make_float2(acc[r][0], acc[r][1]);
}

// ---------------- Kernel B: sum 32 partials + RMSNorm + RoPE ----------------
// grid 512 = 16 type-heads (8 q, 4 k, 4 v) x 32 seq
__global__ __launch_bounds__(256) void k_rms_rope(
    const float* __restrict__ part,
    const float* __restrict__ cosb, const float* __restrict__ sinb,
    const float* __restrict__ qw, const float* __restrict__ kw, const float* __restrict__ vw,
    float* __restrict__ q, float* __restrict__ kn, float* __restrict__ vn)
{
    const int b = blockIdx.x;
    const int th = b >> 5;     // 0..15
    const int s  = b & 31;
    const int d  = threadIdx.x;
    const float* w; float* op; int col; bool rope;
    if (th < 8)       { w = qw; col = th * 256;               op = q  + ((size_t)(th * 32 + s)) * 256;        rope = true;  }
    else if (th < 12) { w = kw; col = 2048 + (th - 8) * 256;  op = kn + ((size_t)((th - 8) * 32 + s)) * 256;  rope = true;  }
    else              { w = vw; col = 3072 + (th - 12) * 256; op = vn + ((size_t)((th - 12) * 32 + s)) * 256; rope = false; }
    const int base = s * 4096 + col + d;
    float a[8] = {};
    #pragma unroll
    for (int p = 0; p < 32; p += 8) {
        #pragma unroll
        for (int j = 0; j < 8; j++)
            a[j] += part[(size_t)(p + j) * 131072 + base];
    }
    float x = ((a[0]+a[1])+(a[2]+a[3])) + ((a[4]+a[5])+(a[6]+a[7]));
    float ss = x * x;
    #pragma unroll
    for (int m = 32; m; m >>= 1) ss += __shfl_xor(ss, m, 64);
    __shared__ float red[4];
    __shared__ float xs[256];
    if ((threadIdx.x & 63) == 0) red[threadIdx.x >> 6] = ss;
    __syncthreads();
    float tot = red[0] + red[1] + red[2] + red[3];
    float xn = x * rsqrtf(tot * (1.0f / 256.0f) + 1e-6f) * w[d];
    xs[d] = xn;
    __syncthreads();
    float out = xn;
    if (rope) {
        float rot = (d < 128) ? -xs[d + 128] : xs[d - 128];
        out = xn * cosb[s * 256 + d] + rot * sinb[s * 256 + d];
    }
    op[d] = out;
}

// ---------------- Kernel C: fused flash attention chunk ----------------
// grid (128 l-chunks of 64, 4 kv), block 512 (8 waves; wave owns 8 q-rows, lane owns 1 key).
// Writes per-chunk unnormalized PV + (rowmax, rowsum) stats. Logits never hit HBM.
__global__ __launch_bounds__(512) void k_attn(
    const float* __restrict__ qb,       // [KV][64][256]
    const float* __restrict__ cache_k, const float* __restrict__ knb,
    const float* __restrict__ cache_v, const float* __restrict__ vnb,
    const float* __restrict__ mask,     // [32][L]
    float* __restrict__ pvpart,         // [128][KV][64][256]
    float* __restrict__ mstat,          // [128][KV][64]
    float* __restrict__ lstat)          // [128][KV][64]
{
    const int chunk = blockIdx.x;
    const int kh    = blockIdx.y;
    const int l0    = chunk * 64;
    const int tid   = threadIdx.x;
    const int lane  = tid & 63;
    const int r0    = (tid >> 6) * 8;

    __shared__ __align__(16) float qs[64][68];      // [q][d-chunk 64]
    __shared__ __align__(16) float ks[64][64];      // [key][d-chunk 64], XOR-swizzled
    __shared__ __align__(16) float ps[64][68];      // [q][key] exp'd
    __shared__ __align__(16) float vs[2][8][260];   // [buf][l][d]

    // ---- QK^T over 4 d-chunks of 64 ----
    float s[8] = {};
    for (int dch = 0; dch < 4; dch++) {
        const int d0 = dch * 64;
        #pragma unroll
        for (int i = 0; i < 2; i++) {
            int idx = i * 512 + tid;                // 1024 float4
            int qq = idx >> 4, g = idx & 15;
            *(float4*)&qs[qq][g * 4] =
                *(const float4*)&qb[((size_t)kh * 64 + qq) * 256 + d0 + g * 4];
        }
        #pragma unroll
        for (int i = 0; i < 2; i++) {
            int idx = i * 512 + tid;
            int l = idx >> 4, g = idx & 15;
            int labs = l0 + l;
            const float* src = (labs < LKEEP_)
                ? &cache_k[((size_t)kh * L_ + labs + S_) * 256 + d0 + g * 4]
                : &knb[((size_t)kh * S_ + (labs - LKEEP_)) * 256 + d0 + g * 4];
            *(float4*)&ks[l][(g ^ (l & 15)) * 4] = *(const float4*)src;   // swizzle store
        }
        __syncthreads();
        #pragma unroll
        for (int g = 0; g < 16; g++) {
            float4 kv = *(const float4*)&ks[lane][(g ^ (lane & 15)) * 4]; // swizzle read
            #pragma unroll
            for (int i = 0; i < 8; i++) {
                float4 qv = *(const float4*)&qs[r0 + i][g * 4];           // broadcast
                s[i] = fmaf(qv.x, kv.x, s[i]);
                s[i] = fmaf(qv.y, kv.y, s[i]);
                s[i] = fmaf(qv.z, kv.z, s[i]);
                s[i] = fmaf(qv.w, kv.w, s[i]);
            }
        }
        __syncthreads();
    }

    // ---- mask + per-chunk online softmax (wave shuffle reduce over 64 keys) ----
    #pragma unroll
    for (int i = 0; i < 8; i++)
        s[i] += mask[(size_t)((r0 + i) & 31) * L_ + l0 + lane];
    float mloc[8], lloc[8];
    #pragma unroll
    for (int i = 0; i < 8; i++) {
        float mm = s[i];
        #pragma unroll
        for (int off = 32; off; off >>= 1) mm = fmaxf(mm, __shfl_xor(mm, off, 64));
        float pp = __expf(s[i] - mm);
        float ssum = pp;
        #pragma unroll
        for (int off = 32; off; off >>= 1) ssum += __shfl_xor(ssum, off, 64);
        mloc[i] = mm; lloc[i] = ssum;
        ps[r0 + i][lane] = pp;
    }
    if (lane == 0) {
        #pragma unroll
        for (int i = 0; i < 8; i++) {
            mstat[((size_t)chunk * KV_ + kh) * 64 + r0 + i] = mloc[i];
            lstat[((size_t)chunk * KV_ + kh) * 64 + r0 + i] = lloc[i];
        }
    }

    // ---- PV: lane owns 4 d-cols, wave owns same 8 q-rows; V double-buffered 8-l chunks ----
    {
        int l = tid >> 6, dg = tid & 63;
        int labs = l0 + l;
        const float* src = (labs < LKEEP_)
            ? &cache_v[((size_t)kh * L_ + labs + S_) * 256 + dg * 4]
            : &vnb[((size_t)kh * S_ + (labs - LKEEP_)) * 256 + dg * 4];
        *(float4*)&vs[0][l][dg * 4] = *(const float4*)src;
    }
    __syncthreads();
    float o[8][4] = {};
    for (int vc = 0; vc < 8; vc++) {
        const int cur = vc & 1;
        if (vc < 7) {
            int l = tid >> 6, dg = tid & 63;
            int labs = l0 + (vc + 1) * 8 + l;
            const float* src = (labs < LKEEP_)
                ? &cache_v[((size_t)kh * L_ + labs + S_) * 256 + dg * 4]
                : &vnb[((size_t)kh * S_ + (labs - LKEEP_)) * 256 + dg * 4];
            *(float4*)&vs[cur ^ 1][l][dg * 4] = *(const float4*)src;
        }
        #pragma unroll
        for (int l4 = 0; l4 < 2; l4++) {
            float4 pv[8];
            #pragma unroll
            for (int i = 0; i < 8; i++)
                pv[i] = *(const float4*)&ps[r0 + i][vc * 8 + l4 * 4];     // broadcast
            #pragma unroll
            for (int ll = 0; ll < 4; ll++) {
                float4 vv = *(const float4*)&vs[cur][l4 * 4 + ll][lane * 4];
                #pragma unroll
                for (int i = 0; i < 8; i++) {
                    float pp = ((const float*)&pv[i])[ll];
                    o[i][0] = fmaf(pp, vv.x, o[i][0]);
                    o[i][1] = fmaf(pp, vv.y, o[i][1]);
                    o[i][2] = fmaf(pp, vv.z, o[i][2]);
                    o[i][3] = fmaf(pp, vv.w, o[i][3]);
                }
            }
        }
        __syncthreads();
    }
    float* op = pvpart + ((size_t)chunk * KV_ + kh) * (64 * 256);
    #pragma unroll
    for (int i = 0; i < 8; i++)
        *(float4*)&op[(r0 + i) * 256 + lane * 4] =
            make_float4(o[i][0], o[i][1], o[i][2], o[i][3]);
}

// ---------------- Kernel D: combine 128 chunks (online softmax) + interleave ----------------
// grid 256 = (kh*64+n), block 256: 4 chunk-groups x 64 d-lanes (float4).
__global__ __launch_bounds__(256) void k_pvcomb(
    const float* __restrict__ pvpart,
    const float* __restrict__ mstat, const float* __restrict__ lstat,
    float* __restrict__ attn)
{
    const int b = blockIdx.x;
    const int kh = b >> 6, n = b & 63;
    const int tid = threadIdx.x;
    const int tg = tid >> 6, dl = tid & 63;
    __shared__ float ms_[NCH_], ls_[NCH_], ws_[NCH_];
    __shared__ __align__(16) float red[4][64][4];

    if (tid < NCH_) {
        ms_[tid] = mstat[((size_t)tid * KV_ + kh) * 64 + n];
        ls_[tid] = lstat[((size_t)tid * KV_ + kh) * 64 + n];
    }
    __syncthreads();
    float M = -1e30f;
    for (int c = 0; c < NCH_; c++) M = fmaxf(M, ms_[c]);
    if (tid < NCH_) ws_[tid] = __expf(ms_[tid] - M);
    __syncthreads();
    float denom = 0.f;
    for (int c = 0; c < NCH_; c++) denom += ws_[c] * ls_[c];

    float4 a[8];
    #pragma unroll
    for (int j = 0; j < 8; j++) a[j] = make_float4(0.f, 0.f, 0.f, 0.f);
    for (int cc = 0; cc < 32; cc += 8) {
        #pragma unroll
        for (int j = 0; j < 8; j++) {
            int c = (cc + j) * 4 + tg;
            float w = ws_[c];
            float4 v = *(const float4*)&pvpart[(((size_t)c * KV_ + kh) * 64 + n) * 256 + dl * 4];
            a[j].x = fmaf(w, v.x, a[j].x); a[j].y = fmaf(w, v.y, a[j].y);
            a[j].z = fmaf(w, v.z, a[j].z); a[j].w = fmaf(w, v.w, a[j].w);
        }
    }
    float4 t;
    t.x = ((a[0].x+a[1].x)+(a[2].x+a[3].x)) + ((a[4].x+a[5].x)+(a[6].x+a[7].x));
    t.y = ((a[0].y+a[1].y)+(a[2].y+a[3].y)) + ((a[4].y+a[5].y)+(a[6].y+a[7].y));
    t.z = ((a[0].z+a[1].z)+(a[2].z+a[3].z)) + ((a[4].z+a[5].z)+(a[6].z+a[7].z));
    t.w = ((a[0].w+a[1].w)+(a[2].w+a[3].w)) + ((a[4].w+a[5].w)+(a[6].w+a[7].w));
    *(float4*)&red[tg][dl][0] = t;
    __syncthreads();
    if (tid < 64) {
        float4 r0 = *(const float4*)&red[0][tid][0];
        float4 r1 = *(const float4*)&red[1][tid][0];
        float4 r2 = *(const float4*)&red[2][tid][0];
        float4 r3 = *(const float4*)&red[3][tid][0];
        float inv = 1.0f / denom;
        float4 o = make_float4((r0.x+r1.x+r2.x+r3.x) * inv, (r0.y+r1.y+r2.y+r3.y) * inv,
                               (r0.z+r1.z+r2.z+r3.z) * inv, (r0.w+r1.w+r2.w+r3.w) * inv);
        const int h = kh * 2 + (n >> 5), srow = n & 31;
        *(float4*)&attn[(size_t)srow * 2048 + h * 256 + tid * 4] = o;
    }
}

// ---------------- Kernel E: W_o GEMM, K-split x32 into partials ----------------
// grid (5 col-tiles of 512, 32 k-splits of 64), block 256. 16-deep W prefetch ring.
__global__ __launch_bounds__(256) void k_out(
    const float* __restrict__ attn, const float* __restrict__ Wo,
    float* __restrict__ opart)
{
    const int col0  = blockIdx.x * 512;
    const int kbase = blockIdx.y * 64;
    const int tid   = threadIdx.x;
    const int tc    = tid * 2;

    __shared__ __align__(16) float hsT[64][36];
    #pragma unroll
    for (int i = 0; i < 2; i++) {
        int idx = i * 256 + tid;            // 512 float4 = 32r x 16c4
        int r = idx >> 4, c4 = idx & 15;
        float4 v = *(const float4*)&attn[r * 2048 + kbase + c4 * 4];
        hsT[c4*4+0][r] = v.x; hsT[c4*4+1][r] = v.y;
        hsT[c4*4+2][r] = v.z; hsT[c4*4+3][r] = v.w;
    }
    __syncthreads();

    const float* Wt = Wo + (size_t)kbase * 2560 + col0 + tc;
    float acc[32][2] = {};
#define FMABLK(k, wc) \
    _Pragma("unroll") for (int r4 = 0; r4 < 8; r4++) { \
      float4 h = *(const float4*)&hsT[(k)][r4*4]; \
      acc[r4*4+0][0] = fmaf(h.x, wc.x, acc[r4*4+0][0]); acc[r4*4+0][1] = fmaf(h.x, wc.y, acc[r4*4+0][1]); \
      acc[r4*4+1][0] = fmaf(h.y, wc.x, acc[r4*4+1][0]); acc[r4*4+1][1] = fmaf(h.y, wc.y, acc[r4*4+1][1]); \
      acc[r4*4+2][0] = fmaf(h.z, wc.x, acc[r4*4+2][0]); acc[r4*4+2][1] = fmaf(h.z, wc.y, acc[r4*4+2][1]); \
      acc[r4*4+3][0] = fmaf(h.w, wc.x, acc[r4*4+3][0]); acc[r4*4+3][1] = fmaf(h.w, wc.y, acc[r4*4+3][1]); }

    float2 wr[16];
    #pragma unroll
    for (int j = 0; j < 16; j++) wr[j] = *(const float2*)&Wt[(size_t)j * 2560];
    for (int ib = 0; ib < 48; ib += 16) {          // ib = 0,16,32
        #pragma unroll
        for (int j = 0; j < 16; j++) {
            float2 wc = wr[j];
            wr[j] = *(const float2*)&Wt[(size_t)(ib + j + 16) * 2560];
            FMABLK(ib + j, wc)
        }
    }
    #pragma unroll
    for (int j = 0; j < 16; j++) { float2 wc = wr[j]; FMABLK(48 + j, wc) }
#undef FMABLK

    float* op = opart + (size_t)blockIdx.y * (32 * 2560);
    #pragma unroll
    for (int r = 0; r < 32; r++)
        *(float2*)&op[r * 2560 + col0 + tc] = make_float2(acc[r][0], acc[r][1]);
}

// ---------------- Kernel F: sum 32 W_o partials into d_out ----------------
__global__ __launch_bounds__(256) void k_osum(const float* __restrict__ opart,
                                              float* __restrict__ out)
{
    int idx = blockIdx.x * 256 + threadIdx.x;   // 320 blocks -> 81920
    float a[8] = {};
    #pragma unroll
    for (int p = 0; p < 32; p += 8) {
        #pragma unroll
        for (int j = 0; j < 8; j++)
            a[j] += opart[(size_t)(p + j) * 81920 + idx];
    }
    out[idx] = ((a[0]+a[1])+(a[2]+a[3])) + ((a[4]+a[5])+(a[6]+a[7]));
}

// ---------------- host ----------------
extern "C" void kernel_launch(void* const* d_in, const int* in_sizes, int n_in,
                              void* d_out, int out_size, void* d_ws, size_t ws_size,
                              hipStream_t stream)
{
    const float* hidden  = (const float*)d_in[0];
    const float* cosb    = (const float*)d_in[1];
    const float* sinb    = (const float*)d_in[2];
    const float* cache_k = (const float*)d_in[3];
    const float* cache_v = (const float*)d_in[4];
    const float* mask    = (const float*)d_in[5];
    const float* Wq      = (const float*)d_in[6];
    const float* Wk      = (const float*)d_in[7];
    const float* Wv      = (const float*)d_in[8];
    const float* Wo      = (const float*)d_in[9];
    const float* qw      = (const float*)d_in[10];
    const float* kw      = (const float*)d_in[11];
    const float* vw      = (const float*)d_in[12];

    float* ws = (float*)d_ws;
    // Region A (8,388,608 floats) time-shared: qkv partials -> pv partials -> Wo partials
    float* A      = ws;
    float* qb     = ws + 8388608;           // 65,536
    float* knb    = ws + 8454144;           // 32,768
    float* vnb    = ws + 8486912;           // 32,768
    float* mstat  = ws + 8519680;           // 32,768
    float* lstat  = ws + 8552448;           // 32,768
    float* attn   = ws + 8585216;           // 65,536   (total ~34.6 MB)

    float* qkvp   = A;      // [32][32][4096]
    float* pvpart = A;      // [128][4][64][256]
    float* opart  = A;      // [32][32][2560]

    k_qkv<<<dim3(8, 32), 256, 0, stream>>>(hidden, Wq, Wk, Wv, qkvp);
    k_rms_rope<<<512, 256, 0, stream>>>(qkvp, cosb, sinb, qw, kw, vw, qb, knb, vnb);
    k_attn<<<dim3(NCH_, KV_), 512, 0, stream>>>(qb, cache_k, knb, cache_v, vnb, mask,
                                                pvpart, mstat, lstat);
    k_pvcomb<<<256, 256, 0, stream>>>(pvpart, mstat, lstat, attn);
    k_out<<<dim3(5, 32), 256, 0, stream>>>(attn, Wo, opart);
    k_osum<<<320, 256, 0, stream>>>(opart, (float*)d_out);
}

// Round 8
// 211.518 us; speedup vs baseline: 1.2704x; 1.2704x over previous
//
#include <hip/hip_runtime.h>
#include <hip/hip_bf16.h>
#include <hip/hip_fp16.h>
#include <cstdint>
#include <cstddef>

#define H_     8
#define KV_    4
#define D_     256
#define HID_   2560
#define S_     32
#define L_     8192
#define NQ_    64          // G*S query rows per kv head
#define LKEEP_ (L_ - S_)   // 8160
#define NCH_   128         // attention l-chunks of 64

typedef unsigned short u16x8 __attribute__((ext_vector_type(8)));
typedef __bf16         bf16x8 __attribute__((ext_vector_type(8)));
typedef float          f32x4  __attribute__((ext_vector_type(4)));

#define TOBF(v) __builtin_bit_cast(bf16x8, v)
#define MFMA16(a, b, c) __builtin_amdgcn_mfma_f32_16x16x32_bf16(TOBF(a), TOBF(b), (c), 0, 0, 0)

__device__ __forceinline__ unsigned short bf16_rne(float x) {
    unsigned u = __float_as_uint(x);
    unsigned r = (u + 0x7FFFu + ((u >> 16) & 1u)) >> 16;
    return (unsigned short)r;
}
__device__ __forceinline__ float bf16_to_f(unsigned short h) {
    return __uint_as_float((unsigned)h << 16);
}

// ---------------- Kernel A: QKV projection, K-split x32 into partials ----------------
// part[32][32][4096]; cols 0..2047 Wq, 2048..3071 Wk, 3072..4095 Wv.
// grid (8 col-tiles of 512, 32 k-splits of 80), block 256. 16-deep W prefetch ring.
__global__ __launch_bounds__(256) void k_qkv(
    const float* __restrict__ hidden,
    const float* __restrict__ Wq, const float* __restrict__ Wk, const float* __restrict__ Wv,
    float* __restrict__ part)
{
    const int col0  = blockIdx.x * 512;
    const int kbase = blockIdx.y * 80;
    const float* W; int ldw, wb;
    if (col0 < 2048)      { W = Wq; ldw = 2048; wb = col0; }
    else if (col0 < 3072) { W = Wk; ldw = 1024; wb = col0 - 2048; }
    else                  { W = Wv; ldw = 1024; wb = col0 - 3072; }
    const int tid = threadIdx.x;
    const int tc  = tid * 2;

    __shared__ __align__(16) float hsT[80][36];   // [k][row]
    for (int i = 0; i < 3; i++) {
        int idx = i * 256 + tid;
        if (idx < 640) {
            int r = idx / 20, c4 = idx % 20;
            float4 v = *(const float4*)&hidden[r * HID_ + kbase + c4 * 4];
            hsT[c4*4+0][r] = v.x; hsT[c4*4+1][r] = v.y;
            hsT[c4*4+2][r] = v.z; hsT[c4*4+3][r] = v.w;
        }
    }
    __syncthreads();

    const float* Wt = W + (size_t)kbase * ldw + wb + tc;
    float acc[32][2] = {};
#define FMABLK(k, wc) \
    _Pragma("unroll") for (int r4 = 0; r4 < 8; r4++) { \
      float4 h = *(const float4*)&hsT[(k)][r4*4]; \
      acc[r4*4+0][0] = fmaf(h.x, wc.x, acc[r4*4+0][0]); acc[r4*4+0][1] = fmaf(h.x, wc.y, acc[r4*4+0][1]); \
      acc[r4*4+1][0] = fmaf(h.y, wc.x, acc[r4*4+1][0]); acc[r4*4+1][1] = fmaf(h.y, wc.y, acc[r4*4+1][1]); \
      acc[r4*4+2][0] = fmaf(h.z, wc.x, acc[r4*4+2][0]); acc[r4*4+2][1] = fmaf(h.z, wc.y, acc[r4*4+2][1]); \
      acc[r4*4+3][0] = fmaf(h.w, wc.x, acc[r4*4+3][0]); acc[r4*4+3][1] = fmaf(h.w, wc.y, acc[r4*4+3][1]); }

    float2 wr[16];
    #pragma unroll
    for (int j = 0; j < 16; j++) wr[j] = *(const float2*)&Wt[(size_t)j * ldw];
    for (int ib = 0; ib < 64; ib += 16) {          // ib = 0,16,32,48
        #pragma unroll
        for (int j = 0; j < 16; j++) {
            float2 wc = wr[j];
            wr[j] = *(const float2*)&Wt[(size_t)(ib + j + 16) * ldw];
            FMABLK(ib + j, wc)
        }
    }
    #pragma unroll
    for (int j = 0; j < 16; j++) { float2 wc = wr[j]; FMABLK(64 + j, wc) }
#undef FMABLK

    float* op = part + (size_t)blockIdx.y * (32 * 4096);
    #pragma unroll
    for (int r = 0; r < 32; r++)
        *(float2*)&op[r * 4096 + col0 + tc] = make_float2(acc[r][0], acc[r][1]);
}

// ---------------- Kernel B: sum 32 partials + RMSNorm + RoPE ----------------
__global__ __launch_bounds__(256) void k_rms_rope(
    const float* __restrict__ part,
    const float* __restrict__ cosb, const float* __restrict__ sinb,
    const float* __restrict__ qw, const float* __restrict__ kw, const float* __restrict__ vw,
    float* __restrict__ q, float* __restrict__ kn, float* __restrict__ vn)
{
    const int b = blockIdx.x;
    const int th = b >> 5;     // 0..15
    const int s  = b & 31;
    const int d  = threadIdx.x;
    const float* w; float* op; int col; bool rope;
    if (th < 8)       { w = qw; col = th * 256;               op = q  + ((size_t)(th * 32 + s)) * 256;        rope = true;  }
    else if (th < 12) { w = kw; col = 2048 + (th - 8) * 256;  op = kn + ((size_t)((th - 8) * 32 + s)) * 256;  rope = true;  }
    else              { w = vw; col = 3072 + (th - 12) * 256; op = vn + ((size_t)((th - 12) * 32 + s)) * 256; rope = false; }
    const int base = s * 4096 + col + d;
    float a[8] = {};
    #pragma unroll
    for (int p = 0; p < 32; p += 8) {
        #pragma unroll
        for (int j = 0; j < 8; j++)
            a[j] += part[(size_t)(p + j) * 131072 + base];
    }
    float x = ((a[0]+a[1])+(a[2]+a[3])) + ((a[4]+a[5])+(a[6]+a[7]));
    float ss = x * x;
    #pragma unroll
    for (int m = 32; m; m >>= 1) ss += __shfl_xor(ss, m, 64);
    __shared__ float red[4];
    __shared__ float xs[256];
    if ((threadIdx.x & 63) == 0) red[threadIdx.x >> 6] = ss;
    __syncthreads();
    float tot = red[0] + red[1] + red[2] + red[3];
    float xn = x * rsqrtf(tot * (1.0f / 256.0f) + 1e-6f) * w[d];
    xs[d] = xn;
    __syncthreads();
    float out = xn;
    if (rope) {
        float rot = (d < 128) ? -xs[d + 128] : xs[d - 128];
        out = xn * cosb[s * 256 + d] + rot * sinb[s * 256 + d];
    }
    op[d] = out;
}

// ---------------- Kernel C: fused flash attention chunk — MFMA bf16 3-term split ----
// grid (128 chunks of 64 keys, 4 kv), block 256 (4 waves).
// Wave w owns q-rows [w*16, w*16+16) x all 64 keys of the chunk.
// LDS tiles [64][72] bf16 (144B row stride, rows 16B-aligned):
//   QK phase: [0]=Qhi [1]=Qlo [2]=Khi [3]=Klo  (per 64-d chunk, x4)
//   PV phase: [0]=vT_hi [1]=vT_lo (per 64-d quarter, x4), [2]=Phi [3]=Plo (resident)
__global__ __launch_bounds__(256) void k_attn(
    const float* __restrict__ qb,       // [KV][64][256]
    const float* __restrict__ cache_k, const float* __restrict__ knb,
    const float* __restrict__ cache_v, const float* __restrict__ vnb,
    const float* __restrict__ mask,     // [32][L]
    __half* __restrict__ pvpart,        // [128][KV][64][256] fp16
    float* __restrict__ mstat,          // [128][KV][64]
    float* __restrict__ lstat)          // [128][KV][64]
{
    const int chunk = blockIdx.x;
    const int kh    = blockIdx.y;
    const int l0    = chunk * 64;
    const int tid   = threadIdx.x;
    const int lane  = tid & 63;
    const int wid   = tid >> 6;         // 0..3 = q-tile
    const int lr    = lane & 15;        // frag row/col-select
    const int lg    = lane >> 4;        // frag k-slice group (0..3)

    __shared__ __align__(16) unsigned short lds4[4][64][72];   // 36864 B

    // ---------------- QK^T: accumulate S over 4 d-chunks ----------------
    f32x4 accS[4] = {};                 // per key-tile kt
    for (int dch = 0; dch < 4; dch++) {
        const int d0 = dch * 64;
        if (dch) __syncthreads();       // prior compute reads done before restaging
        // stage Q,K [64 rows][64 d] as hi/lo bf16 (2 row-groups of 8 floats per thread)
        #pragma unroll
        for (int i = 0; i < 2; i++) {
            int G   = i * 256 + tid;    // 0..511
            int row = G >> 3;
            int dg  = (G & 7) * 8;
            {
                const float* s = &qb[((size_t)kh * 64 + row) * 256 + d0 + dg];
                float4 x0 = *(const float4*)s, x1 = *(const float4*)(s + 4);
                float xv[8] = {x0.x, x0.y, x0.z, x0.w, x1.x, x1.y, x1.z, x1.w};
                u16x8 h, l;
                #pragma unroll
                for (int j = 0; j < 8; j++) {
                    unsigned short hb = bf16_rne(xv[j]);
                    h[j] = hb;
                    l[j] = bf16_rne(xv[j] - bf16_to_f(hb));
                }
                *(u16x8*)&lds4[0][row][dg] = h;
                *(u16x8*)&lds4[1][row][dg] = l;
            }
            {
                int labs = l0 + row;
                const float* s = (labs < LKEEP_)
                    ? &cache_k[((size_t)kh * L_ + labs + S_) * 256 + d0 + dg]
                    : &knb[((size_t)kh * S_ + (labs - LKEEP_)) * 256 + d0 + dg];
                float4 x0 = *(const float4*)s, x1 = *(const float4*)(s + 4);
                float xv[8] = {x0.x, x0.y, x0.z, x0.w, x1.x, x1.y, x1.z, x1.w};
                u16x8 h, l;
                #pragma unroll
                for (int j = 0; j < 8; j++) {
                    unsigned short hb = bf16_rne(xv[j]);
                    h[j] = hb;
                    l[j] = bf16_rne(xv[j] - bf16_to_f(hb));
                }
                *(u16x8*)&lds4[2][row][dg] = h;
                *(u16x8*)&lds4[3][row][dg] = l;
            }
        }
        __syncthreads();
        #pragma unroll
        for (int ks = 0; ks < 2; ks++) {
            const int off = ks * 32 + lg * 8;
            u16x8 aH = *(const u16x8*)&lds4[0][wid * 16 + lr][off];
            u16x8 aL = *(const u16x8*)&lds4[1][wid * 16 + lr][off];
            #pragma unroll
            for (int kt = 0; kt < 4; kt++) {
                u16x8 bH = *(const u16x8*)&lds4[2][kt * 16 + lr][off];
                u16x8 bL = *(const u16x8*)&lds4[3][kt * 16 + lr][off];
                accS[kt] = MFMA16(aH, bH, accS[kt]);
                accS[kt] = MFMA16(aH, bL, accS[kt]);
                accS[kt] = MFMA16(aL, bH, accS[kt]);
            }
        }
    }
    __syncthreads();   // all QK reads done before P/V overwrite LDS

    // ---------------- softmax on C-layout: S[q=wid*16+lg*4+r][key=kt*16+lr] ----------
    float pbuf[4][4];                   // [r][kt]
    float mrow[4], lrow[4];
    #pragma unroll
    for (int r = 0; r < 4; r++) {
        const int qrow = wid * 16 + lg * 4 + r;
        const int srow = qrow & 31;
        float sv[4];
        #pragma unroll
        for (int kt = 0; kt < 4; kt++)
            sv[kt] = accS[kt][r] + mask[(size_t)srow * L_ + l0 + kt * 16 + lr];
        float mm = fmaxf(fmaxf(sv[0], sv[1]), fmaxf(sv[2], sv[3]));
        #pragma unroll
        for (int off = 8; off; off >>= 1) mm = fmaxf(mm, __shfl_xor(mm, off, 64));
        float ssum = 0.f;
        #pragma unroll
        for (int kt = 0; kt < 4; kt++) {
            float p = __expf(sv[kt] - mm);
            pbuf[r][kt] = p;
            ssum += p;
        }
        #pragma unroll
        for (int off = 8; off; off >>= 1) ssum += __shfl_xor(ssum, off, 64);
        mrow[r] = mm;
        lrow[r] = ssum;
    }
    if (lr == 0) {
        #pragma unroll
        for (int r = 0; r < 4; r++) {
            int qrow = wid * 16 + lg * 4 + r;
            mstat[((size_t)chunk * KV_ + kh) * 64 + qrow] = mrow[r];
            lstat[((size_t)chunk * KV_ + kh) * 64 + qrow] = lrow[r];
        }
    }
    // write P hi/lo into lds4[2],[3] (own rows only -> no cross-wave race)
    #pragma unroll
    for (int r = 0; r < 4; r++) {
        const int qrow = wid * 16 + lg * 4 + r;
        #pragma unroll
        for (int kt = 0; kt < 4; kt++) {
            float p = pbuf[r][kt];
            unsigned short ph = bf16_rne(p);
            lds4[2][qrow][kt * 16 + lr] = ph;
            lds4[3][qrow][kt * 16 + lr] = bf16_rne(p - bf16_to_f(ph));
        }
    }

    // ---------------- PV: O[64q][256d] over 4 d-quarters ----------------
    f32x4 accO[16] = {};
    #pragma unroll
    for (int qd = 0; qd < 4; qd++) {
        // stage vT quarter: wave stages its 16 local d-rows; lane = key col
        {
            const int labs = l0 + lane;
            const float* s = (labs < LKEEP_)
                ? &cache_v[((size_t)kh * L_ + labs + S_) * 256 + qd * 64 + wid * 16]
                : &vnb[((size_t)kh * S_ + (labs - LKEEP_)) * 256 + qd * 64 + wid * 16];
            float4 x0 = *(const float4*)s,       x1 = *(const float4*)(s + 4);
            float4 x2 = *(const float4*)(s + 8), x3 = *(const float4*)(s + 12);
            float xv[16] = {x0.x, x0.y, x0.z, x0.w, x1.x, x1.y, x1.z, x1.w,
                            x2.x, x2.y, x2.z, x2.w, x3.x, x3.y, x3.z, x3.w};
            #pragma unroll
            for (int j = 0; j < 16; j++) {
                unsigned short hb = bf16_rne(xv[j]);
                lds4[0][wid * 16 + j][lane] = hb;
                lds4[1][wid * 16 + j][lane] = bf16_rne(xv[j] - bf16_to_f(hb));
            }
        }
        __syncthreads();
        #pragma unroll
        for (int ks = 0; ks < 2; ks++) {
            const int off = ks * 32 + lg * 8;
            u16x8 pH = *(const u16x8*)&lds4[2][wid * 16 + lr][off];
            u16x8 pL = *(const u16x8*)&lds4[3][wid * 16 + lr][off];
            #pragma unroll
            for (int dt = 0; dt < 4; dt++) {
                u16x8 vH = *(const u16x8*)&lds4[0][dt * 16 + lr][off];
                u16x8 vL = *(const u16x8*)&lds4[1][dt * 16 + lr][off];
                accO[qd * 4 + dt] = MFMA16(pH, vH, accO[qd * 4 + dt]);
                accO[qd * 4 + dt] = MFMA16(pH, vL, accO[qd * 4 + dt]);
                accO[qd * 4 + dt] = MFMA16(pL, vH, accO[qd * 4 + dt]);
            }
        }
        __syncthreads();
    }
    // write O partial (fp16): C-layout row=q, col=d
    __half* op = pvpart + ((size_t)chunk * KV_ + kh) * (64 * 256);
    #pragma unroll
    for (int g = 0; g < 16; g++) {
        #pragma unroll
        for (int j = 0; j < 4; j++) {
            int qrow = wid * 16 + lg * 4 + j;
            op[(size_t)qrow * 256 + g * 16 + lr] = __float2half(accO[g][j]);
        }
    }
}

// ---------------- Kernel D: combine 128 chunks (online softmax) + interleave ----------
// grid 256 = (kh*64+n), block 256: 4 chunk-groups x 64 d-lanes (4 halves each).
__global__ __launch_bounds__(256) void k_pvcomb(
    const __half* __restrict__ pvpart,
    const float* __restrict__ mstat, const float* __restrict__ lstat,
    float* __restrict__ attn)
{
    const int b = blockIdx.x;
    const int kh = b >> 6, n = b & 63;
    const int tid = threadIdx.x;
    const int tg = tid >> 6, dl = tid & 63;
    __shared__ float ms_[NCH_], ls_[NCH_], ws_[NCH_];
    __shared__ __align__(16) float red[4][64][4];

    if (tid < NCH_) {
        ms_[tid] = mstat[((size_t)tid * KV_ + kh) * 64 + n];
        ls_[tid] = lstat[((size_t)tid * KV_ + kh) * 64 + n];
    }
    __syncthreads();
    float M = -1e30f;
    for (int c = 0; c < NCH_; c++) M = fmaxf(M, ms_[c]);
    if (tid < NCH_) ws_[tid] = __expf(ms_[tid] - M);
    __syncthreads();
    float denom = 0.f;
    for (int c = 0; c < NCH_; c++) denom += ws_[c] * ls_[c];

    float4 a[8];
    #pragma unroll
    for (int j = 0; j < 8; j++) a[j] = make_float4(0.f, 0.f, 0.f, 0.f);
    for (int cc = 0; cc < 32; cc += 8) {
        #pragma unroll
        for (int j = 0; j < 8; j++) {
            int c = (cc + j) * 4 + tg;
            float w = ws_[c];
            const __half2* p2 = (const __half2*)&pvpart[(((size_t)c * KV_ + kh) * 64 + n) * 256 + dl * 4];
            float2 f0 = __half22float2(p2[0]);
            float2 f1 = __half22float2(p2[1]);
            a[j].x = fmaf(w, f0.x, a[j].x); a[j].y = fmaf(w, f0.y, a[j].y);
            a[j].z = fmaf(w, f1.x, a[j].z); a[j].w = fmaf(w, f1.y, a[j].w);
        }
    }
    float4 t;
    t.x = ((a[0].x+a[1].x)+(a[2].x+a[3].x)) + ((a[4].x+a[5].x)+(a[6].x+a[7].x));
    t.y = ((a[0].y+a[1].y)+(a[2].y+a[3].y)) + ((a[4].y+a[5].y)+(a[6].y+a[7].y));
    t.z = ((a[0].z+a[1].z)+(a[2].z+a[3].z)) + ((a[4].z+a[5].z)+(a[6].z+a[7].z));
    t.w = ((a[0].w+a[1].w)+(a[2].w+a[3].w)) + ((a[4].w+a[5].w)+(a[6].w+a[7].w));
    *(float4*)&red[tg][dl][0] = t;
    __syncthreads();
    if (tid < 64) {
        float4 r0 = *(const float4*)&red[0][tid][0];
        float4 r1 = *(const float4*)&red[1][tid][0];
        float4 r2 = *(const float4*)&red[2][tid][0];
        float4 r3 = *(const float4*)&red[3][tid][0];
        float inv = 1.0f / denom;
        float4 o = make_float4((r0.x+r1.x+r2.x+r3.x) * inv, (r0.y+r1.y+r2.y+r3.y) * inv,
                               (r0.z+r1.z+r2.z+r3.z) * inv, (r0.w+r1.w+r2.w+r3.w) * inv);
        const int h = kh * 2 + (n >> 5), srow = n & 31;
        *(float4*)&attn[(size_t)srow * 2048 + h * 256 + tid * 4] = o;
    }
}

// ---------------- Kernel E: W_o GEMM, K-split x32 into partials ----------------
// grid (5 col-tiles of 512, 32 k-splits of 64), block 256. 16-deep W prefetch ring.
__global__ __launch_bounds__(256) void k_out(
    const float* __restrict__ attn, const float* __restrict__ Wo,
    float* __restrict__ opart)
{
    const int col0  = blockIdx.x * 512;
    const int kbase = blockIdx.y * 64;
    const int tid   = threadIdx.x;
    const int tc    = tid * 2;

    __shared__ __align__(16) float hsT[64][36];
    #pragma unroll
    for (int i = 0; i < 2; i++) {
        int idx = i * 256 + tid;            // 512 float4 = 32r x 16c4
        int r = idx >> 4, c4 = idx & 15;
        float4 v = *(const float4*)&attn[r * 2048 + kbase + c4 * 4];
        hsT[c4*4+0][r] = v.x; hsT[c4*4+1][r] = v.y;
        hsT[c4*4+2][r] = v.z; hsT[c4*4+3][r] = v.w;
    }
    __syncthreads();

    const float* Wt = Wo + (size_t)kbase * 2560 + col0 + tc;
    float acc[32][2] = {};
#define FMABLK(k, wc) \
    _Pragma("unroll") for (int r4 = 0; r4 < 8; r4++) { \
      float4 h = *(const float4*)&hsT[(k)][r4*4]; \
      acc[r4*4+0][0] = fmaf(h.x, wc.x, acc[r4*4+0][0]); acc[r4*4+0][1] = fmaf(h.x, wc.y, acc[r4*4+0][1]); \
      acc[r4*4+1][0] = fmaf(h.y, wc.x, acc[r4*4+1][0]); acc[r4*4+1][1] = fmaf(h.y, wc.y, acc[r4*4+1][1]); \
      acc[r4*4+2][0] = fmaf(h.z, wc.x, acc[r4*4+2][0]); acc[r4*4+2][1] = fmaf(h.z, wc.y, acc[r4*4+2][1]); \
      acc[r4*4+3][0] = fmaf(h.w, wc.x, acc[r4*4+3][0]); acc[r4*4+3][1] = fmaf(h.w, wc.y, acc[r4*4+3][1]); }

    float2 wr[16];
    #pragma unroll
    for (int j = 0; j < 16; j++) wr[j] = *(const float2*)&Wt[(size_t)j * 2560];
    for (int ib = 0; ib < 48; ib += 16) {          // ib = 0,16,32
        #pragma unroll
        for (int j = 0; j < 16; j++) {
            float2 wc = wr[j];
            wr[j] = *(const float2*)&Wt[(size_t)(ib + j + 16) * 2560];
            FMABLK(ib + j, wc)
        }
    }
    #pragma unroll
    for (int j = 0; j < 16; j++) { float2 wc = wr[j]; FMABLK(48 + j, wc) }
#undef FMABLK

    float* op = opart + (size_t)blockIdx.y * (32 * 2560);
    #pragma unroll
    for (int r = 0; r < 32; r++)
        *(float2*)&op[r * 2560 + col0 + tc] = make_float2(acc[r][0], acc[r][1]);
}

// ---------------- Kernel F: sum 32 W_o partials into d_out ----------------
__global__ __launch_bounds__(256) void k_osum(const float* __restrict__ opart,
                                              float* __restrict__ out)
{
    int idx = blockIdx.x * 256 + threadIdx.x;   // 320 blocks -> 81920
    float a[8] = {};
    #pragma unroll
    for (int p = 0; p < 32; p += 8) {
        #pragma unroll
        for (int j = 0; j < 8; j++)
            a[j] += opart[(size_t)(p + j) * 81920 + idx];
    }
    out[idx] = ((a[0]+a[1])+(a[2]+a[3])) + ((a[4]+a[5])+(a[6]+a[7]));
}

// ---------------- host ----------------
extern "C" void kernel_launch(void* const* d_in, const int* in_sizes, int n_in,
                              void* d_out, int out_size, void* d_ws, size_t ws_size,
                              hipStream_t stream)
{
    const float* hidden  = (const float*)d_in[0];
    const float* cosb    = (const float*)d_in[1];
    const float* sinb    = (const float*)d_in[2];
    const float* cache_k = (const float*)d_in[3];
    const float* cache_v = (const float*)d_in[4];
    const float* mask    = (const float*)d_in[5];
    const float* Wq      = (const float*)d_in[6];
    const float* Wk      = (const float*)d_in[7];
    const float* Wv      = (const float*)d_in[8];
    const float* Wo      = (const float*)d_in[9];
    const float* qw      = (const float*)d_in[10];
    const float* kw      = (const float*)d_in[11];
    const float* vw      = (const float*)d_in[12];

    float* ws = (float*)d_ws;
    // Region A (8,388,608 floats) time-shared: qkv partials -> pv fp16 partials -> Wo partials
    float* A      = ws;
    float* qb     = ws + 8388608;           // 65,536
    float* knb    = ws + 8454144;           // 32,768
    float* vnb    = ws + 8486912;           // 32,768
    float* mstat  = ws + 8519680;           // 32,768
    float* lstat  = ws + 8552448;           // 32,768
    float* attn   = ws + 8585216;           // 65,536   (total ~34.6 MB)

    float*  qkvp   = A;                 // [32][32][4096] f32
    __half* pvpart = (__half*)A;        // [128][4][64][256] fp16 (16.7 MB)
    float*  opart  = A;                 // [32][32][2560] f32

    k_qkv<<<dim3(8, 32), 256, 0, stream>>>(hidden, Wq, Wk, Wv, qkvp);
    k_rms_rope<<<512, 256, 0, stream>>>(qkvp, cosb, sinb, qw, kw, vw, qb, knb, vnb);
    k_attn<<<dim3(NCH_, KV_), 256, 0, stream>>>(qb, cache_k, knb, cache_v, vnb, mask,
                                                pvpart, mstat, lstat);
    k_pvcomb<<<256, 256, 0, stream>>>(pvpart, mstat, lstat, attn);
    k_out<<<dim3(5, 32), 256, 0, stream>>>(attn, Wo, opart);
    k_osum<<<320, 256, 0, stream>>>(opart, (float*)d_out);
}